// Round 3
// baseline (290.967 us; speedup 1.0000x reference)
//
#include <hip/hip_runtime.h>

// mIoU over int32 class maps, NUM=21 (values 0..21; class 0 excluded from iou).
// out[0]=mIoU, out[1..21]=iou for classes 1..21 (f32).
//
// R3: joint 22x22 histogram (1 ds_add/element), hot loop unrolled 4x so each
// thread has 8 independent int4 loads (128 B) in flight before any DS work —
// attacks the measured memory-latency bound (R2: HBM 16.7%, VALU 3.8%).
// Per-block flush goes straight to global atomics (484 bins); partials array
// and reduce kernel removed. g zeroed via hipMemsetAsync.

#define NUMC  21
#define NBINS 22
#define JBINS (NBINS * NBINS)   // 484
#define RSTR  485               // odd replica stride: spreads banks
#define NREP  4                 // one replica per wave (256 threads)
#define GRID  2048

__global__ void __launch_bounds__(256) hist_joint(
        const int* __restrict__ yp, const int* __restrict__ yt,
        unsigned int* __restrict__ g, int n) {
    __shared__ unsigned int h[NREP * RSTR];
    for (int i = threadIdx.x; i < NREP * RSTR; i += 256) h[i] = 0u;
    __syncthreads();

    unsigned int* hh = h + (threadIdx.x >> 6) * RSTR;  // replica per wave

    const int4* __restrict__ yp4 = (const int4*)yp;
    const int4* __restrict__ yt4 = (const int4*)yt;
    const int n4 = n >> 2;
    const int stride = GRID * 256;
    int i = blockIdx.x * 256 + threadIdx.x;

#define DS4(P, T)                                  \
    atomicAdd(&hh[(T).x * NBINS + (P).x], 1u);     \
    atomicAdd(&hh[(T).y * NBINS + (P).y], 1u);     \
    atomicAdd(&hh[(T).z * NBINS + (P).z], 1u);     \
    atomicAdd(&hh[(T).w * NBINS + (P).w], 1u);

    // main: 4x unrolled, 8 independent int4 loads issued before any ds_add
    for (; i + 3 * stride < n4; i += 4 * stride) {
        int4 p0 = yp4[i];
        int4 p1 = yp4[i + stride];
        int4 p2 = yp4[i + 2 * stride];
        int4 p3 = yp4[i + 3 * stride];
        int4 t0 = yt4[i];
        int4 t1 = yt4[i + stride];
        int4 t2 = yt4[i + 2 * stride];
        int4 t3 = yt4[i + 3 * stride];
        DS4(p0, t0) DS4(p1, t1) DS4(p2, t2) DS4(p3, t3)
    }
    // remainder grid-stride iterations
    for (; i < n4; i += stride) {
        int4 p = yp4[i];
        int4 t = yt4[i];
        DS4(p, t)
    }
#undef DS4

    // tail (n % 4 != 0): one thread, straight to global
    if (blockIdx.x == 0 && threadIdx.x == 0) {
        for (int k = n4 << 2; k < n; k++)
            atomicAdd(&g[yt[k] * NBINS + yp[k]], 1u);
    }

    __syncthreads();
    // flush: sum 4 replicas per bin, one global atomic per bin per block
    for (int c = threadIdx.x; c < JBINS; c += 256) {
        unsigned int s = h[c] + h[RSTR + c] + h[2 * RSTR + c] + h[3 * RSTR + c];
        if (s) atomicAdd(&g[c], s);
    }
}

__global__ void finalize_kernel(const unsigned int* __restrict__ g,
                                float* __restrict__ out) {
    int lane = threadIdx.x;  // single wave of 64
    float iou = 0.0f, pres = 0.0f;
    if (lane >= 1 && lane <= NUMC) {
        unsigned int ct = 0, cp = 0;
        #pragma unroll
        for (int k = 0; k < NBINS; k++) {
            ct += g[lane * NBINS + k];   // row sum: cnt_true[lane]
            cp += g[k * NBINS + lane];   // col sum: cnt_pred[lane]
        }
        unsigned int ci = g[lane * NBINS + lane];
        float u = (float)ct + (float)cp - (float)ci;
        iou = ((float)ci + 1e-6f) / (u + 1e-6f);
        pres = (ct > 0u) ? 1.0f : 0.0f;
        out[lane] = iou;  // out[1..21]
    }
    float v = iou * pres, pc = pres;
    #pragma unroll
    for (int off = 32; off > 0; off >>= 1) {
        v += __shfl_down(v, off);
        pc += __shfl_down(pc, off);
    }
    if (lane == 0) out[0] = v / fmaxf(pc, 1.0f);
}

extern "C" void kernel_launch(void* const* d_in, const int* in_sizes, int n_in,
                              void* d_out, int out_size, void* d_ws, size_t ws_size,
                              hipStream_t stream) {
    const int* yp = (const int*)d_in[0];
    const int* yt = (const int*)d_in[1];
    int n = in_sizes[0];
    float* out = (float*)d_out;
    unsigned int* g = (unsigned int*)d_ws;  // 484 joint-bin counters

    hipMemsetAsync(g, 0, JBINS * sizeof(unsigned int), stream);
    hist_joint<<<GRID, 256, 0, stream>>>(yp, yt, g, n);
    finalize_kernel<<<1, 64, 0, stream>>>(g, out);
}

// Round 5
// 260.612 us; speedup vs baseline: 1.1165x; 1.1165x over previous
//
#include <hip/hip_runtime.h>

// mIoU over int32 class maps, NUM=21 (values 0..21; class 0 excluded from iou).
// out[0]=mIoU, out[1..21]=iou for classes 1..21 (f32).
//
// R5 == R4 fixed: __builtin_nontemporal_load needs a NATIVE vector type
// (ext_vector_type), not HIP_vector_type. Joint 22x22 hist, 1 ds_add/elem,
// per-wave LDS replicas, nt streaming loads + 1-deep load rotation,
// non-atomic partials -> reduce -> finalize.

#define NUMC  21
#define NBINS 22
#define JBINS (NBINS * NBINS)   // 484
#define RSTR  485               // odd replica stride: spreads banks
#define NREP  4                 // one replica per wave (256 threads)
#define GRID  2048

typedef int iv4 __attribute__((ext_vector_type(4)));

__global__ void __launch_bounds__(256) hist_joint(
        const int* __restrict__ yp, const int* __restrict__ yt,
        unsigned int* __restrict__ partials, int n) {
    __shared__ unsigned int h[NREP * RSTR];
    for (int i = threadIdx.x; i < NREP * RSTR; i += 256) h[i] = 0u;
    __syncthreads();

    unsigned int* hh = h + (threadIdx.x >> 6) * RSTR;  // replica per wave

    const iv4* __restrict__ yp4 = (const iv4*)yp;
    const iv4* __restrict__ yt4 = (const iv4*)yt;
    const int n4 = n >> 2;
    const int stride = GRID * 256;
    int i = blockIdx.x * 256 + threadIdx.x;

#define DS4(P, T)                                      \
    atomicAdd(&hh[(T).x * NBINS + (P).x], 1u);         \
    atomicAdd(&hh[(T).y * NBINS + (P).y], 1u);         \
    atomicAdd(&hh[(T).z * NBINS + (P).z], 1u);         \
    atomicAdd(&hh[(T).w * NBINS + (P).w], 1u);

    if (i < n4) {
        iv4 p = __builtin_nontemporal_load(yp4 + i);
        iv4 t = __builtin_nontemporal_load(yt4 + i);
        int j = i + stride;
        for (; j < n4; j += stride) {
            iv4 pn = __builtin_nontemporal_load(yp4 + j);  // prefetch next
            iv4 tn = __builtin_nontemporal_load(yt4 + j);
            DS4(p, t)                                       // DS on current
            p = pn; t = tn;
        }
        DS4(p, t)
    }
#undef DS4

    // tail (n % 4 != 0): one thread, into its own replica
    if (blockIdx.x == 0 && threadIdx.x == 0) {
        for (int k = n4 << 2; k < n; k++)
            atomicAdd(&hh[yt[k] * NBINS + yp[k]], 1u);
    }

    __syncthreads();
    // sum the 4 replicas, write this block's partial row (coalesced, no atomics)
    for (int c = threadIdx.x; c < JBINS; c += 256) {
        unsigned int s = h[c] + h[RSTR + c] + h[2 * RSTR + c] + h[3 * RSTR + c];
        partials[(size_t)blockIdx.x * JBINS + c] = s;
    }
}

__global__ void __launch_bounds__(256) reduce_partials(
        const unsigned int* __restrict__ partials,
        unsigned int* __restrict__ g, int nblocks) {
    __shared__ unsigned int lds[256];
    const int c = blockIdx.x;  // one block per joint bin
    unsigned int s = 0;
    for (int b = threadIdx.x; b < nblocks; b += 256)
        s += partials[(size_t)b * JBINS + c];
    lds[threadIdx.x] = s;
    __syncthreads();
    for (int w = 128; w > 0; w >>= 1) {
        if (threadIdx.x < w) lds[threadIdx.x] += lds[threadIdx.x + w];
        __syncthreads();
    }
    if (threadIdx.x == 0) g[c] = lds[0];
}

__global__ void finalize_kernel(const unsigned int* __restrict__ g,
                                float* __restrict__ out) {
    int lane = threadIdx.x;  // single wave of 64
    float iou = 0.0f, pres = 0.0f;
    if (lane >= 1 && lane <= NUMC) {
        unsigned int ct = 0, cp = 0;
        #pragma unroll
        for (int k = 0; k < NBINS; k++) {
            ct += g[lane * NBINS + k];   // row sum: cnt_true[lane]
            cp += g[k * NBINS + lane];   // col sum: cnt_pred[lane]
        }
        unsigned int ci = g[lane * NBINS + lane];
        float u = (float)ct + (float)cp - (float)ci;
        iou = ((float)ci + 1e-6f) / (u + 1e-6f);
        pres = (ct > 0u) ? 1.0f : 0.0f;
        out[lane] = iou;  // out[1..21]
    }
    float v = iou * pres, pc = pres;
    #pragma unroll
    for (int off = 32; off > 0; off >>= 1) {
        v += __shfl_down(v, off);
        pc += __shfl_down(pc, off);
    }
    if (lane == 0) out[0] = v / fmaxf(pc, 1.0f);
}

extern "C" void kernel_launch(void* const* d_in, const int* in_sizes, int n_in,
                              void* d_out, int out_size, void* d_ws, size_t ws_size,
                              hipStream_t stream) {
    const int* yp = (const int*)d_in[0];
    const int* yt = (const int*)d_in[1];
    int n = in_sizes[0];
    float* out = (float*)d_out;

    // ws layout: g[484] | partials[GRID * 484]  (484*4*(2048+1) ≈ 4.0 MB)
    unsigned int* g = (unsigned int*)d_ws;
    unsigned int* partials = g + JBINS;

    hist_joint<<<GRID, 256, 0, stream>>>(yp, yt, partials, n);
    reduce_partials<<<JBINS, 256, 0, stream>>>(partials, g, GRID);
    finalize_kernel<<<1, 64, 0, stream>>>(g, out);
}